// Round 12
// baseline (215.059 us; speedup 1.0000x reference)
//
#include <hip/hip_runtime.h>

// NeuralHashVoxel round 12: cell-validity grids for ALL levels.
//  - bm01 (bucket-valid bitmap, levels 0-1) built with coalesced wave-ballot
//  - occ01_k: vertex-occupancy grids lvl0 (201^3) / lvl1 (101^3) by probing
//    the L2-resident bm01 (9.1M cheap probes) instead of the 32 MB tables
//  - mid_k derives cell grids cbit0 (200^3) / cbit1 (100^3) by AND-shifts
//  - main: ONE cbit load per level (6 total, lane-shared under Morton order)
//    replaces 16 random bitmap probes -> per-point transactions ~25 -> ~9.
//  Scratch: hist/bm01/occ* live in d_out (consumed pre-main); cbit* in ws.

static constexpr int      NPTS  = 1048576;
static constexpr int      NF    = 8;
static constexpr int      TTAB  = 524288;
static constexpr unsigned BTAB  = 4194304u;          // 2^22 buckets per level
static constexpr unsigned BMASK = BTAB - 1u;
static constexpr unsigned P0 = 73856093u, P1 = 19349669u, P2 = 83492791u;

static constexpr int NBIN = 4096;        // 16^3 Morton bins, cell = 3.125
static constexpr int SB   = 256;
static constexpr int PPB  = NPTS / SB;
static constexpr int ITER = PPB / 256;
static constexpr int BCAP = 512;

// vertex-grid dims for levels 2..5 (scaled coords < 50,25,12.5,6.25)
static constexpr int S2 = 51, S3 = 26, S4 = 14, S5 = 8;
static constexpr int OCC2 = 0, OCC3 = OCC2 + S2*S2, OCC4 = OCC3 + S3*S3,
                     OCC5 = OCC4 + S4*S4, OCCW = OCC5 + S5*S5;
static constexpr int CB2 = 0, CB3 = CB2 + (S2-1)*(S2-1),
                     CB4 = CB3 + (S3-1)*(S3-1), CB5 = CB4 + (S4-1)*(S4-1),
                     CBW = CB5 + (S5-1)*(S5-1);                    // 3343
static constexpr int RB2 = (S2*S2+3)/4, RB3 = (S3*S3+3)/4,
                     RB4 = (S4*S4+3)/4, RB5 = (S5*S5+3)/4;
static constexpr int OCCB = RB2+RB3+RB4+RB5;                       // 885

// levels 0-1 dense grids
static constexpr int L0S = 201, L0C = 200, L0W = 4;   // vertices, cells, u64 words/row
static constexpr int L1S = 101, L1C = 100, L1W = 2;
static constexpr int L0R = L0S * L0S;                 // 40401 vertex rows
static constexpr int L1R = L1S * L1S;                 // 10201
static constexpr int OCC0W_CNT = L0R * L0W;           // 161604 u64
static constexpr int OCC1W_CNT = L1R * L1W;           // 20402
static constexpr int CB0_CNT = L0C * L0C * L0W;       // 160000 u64
static constexpr int CB1_CNT = L1C * L1C * L1W;       // 20000
static constexpr int OCC01_WAVES = OCC0W_CNT + OCC1W_CNT;   // 182006
static constexpr int OCC01_B = (OCC01_WAVES + 3) / 4;       // 45502 blocks
static constexpr int MIDC = CBW + CB0_CNT + CB1_CNT;        // 183343
static constexpr int MIDB = 16 + (MIDC + 255) / 256;        // 733

// bm01: wave-ballot layout. bucket B (lvl*BTAB+key):
//   u64 word = ((B>>8)<<2) | (B&3), bit = (B>>2)&63
static constexpr int BM01_WAVES = (int)(2 * BTAB / 256);    // 32768
static constexpr int BM01B = BM01_WAVES / 4;                // 8192 blocks

// d_out scratch layout (all consumed before main kernel writes out)
static constexpr size_t HIST_OFF      = 0;                  // 4 MB
static constexpr size_t OUT_BM01_OFF  = 4u  * 1024 * 1024;  // 1 MB
static constexpr size_t OUT_OCC25_OFF = 5u  * 1024 * 1024;  // ~28 KB
static constexpr size_t OUT_OCC0_OFF  = 5632u * 1024;       // 5.5 MB, 1.3 MB
static constexpr size_t OUT_OCC1_OFF  = 7u  * 1024 * 1024;  // ~160 KB

// ws layout (read by main)
static constexpr size_t SORTED_BYTES = (size_t)NPTS * 16;   // 16 MB
static constexpr size_t CB25_OFF = SORTED_BYTES;
static constexpr size_t CB0_OFF  = CB25_OFF + 32768;
static constexpr size_t CB1_OFF  = CB0_OFF + 1310720;
static constexpr size_t BB_OFF   = CB1_OFF + 163840;
static constexpr size_t WS_FULL  = BB_OFF + (size_t)NBIN * 4;   // ~17.5 MB

typedef float f4 __attribute__((ext_vector_type(4)));
typedef int   i4 __attribute__((ext_vector_type(4)));

// ------------- per-point: all 6 levels gated by cell grids ------------------
__device__ __forceinline__ void nhv_point_g(
    float qx, float qy, float qz,
    const float* __restrict__ feat, const int* __restrict__ fidx,
    const unsigned long long* __restrict__ cbit25,
    const unsigned long long* __restrict__ cbit0,
    const unsigned long long* __restrict__ cbit1, float acc[NF])
{
    // integer cell coords per level (all coords >= 0 -> trunc == floor)
    const int ix0 = (int)(qx * 4.0f), iy0 = (int)(qy * 4.0f), iz0 = (int)(qz * 4.0f);
    const int ix1 = (int)(qx * 2.0f), iy1 = (int)(qy * 2.0f), iz1 = (int)(qz * 2.0f);

    // gate loads for levels 0-1 (dense cell grids, lane-shared under Morton)
    const unsigned long long w0 = cbit0[(size_t)(iz0 * L0C + iy0) * L0W + (ix0 >> 6)];
    const unsigned long long w1 = cbit1[(size_t)(iz1 * L1C + iy1) * L1W + (ix1 >> 6)];

    // levels 2-5: one cbit25 u64 per level (L1-resident)
    float fxh[4], fyh[4], fzh[4];
    int   ixh[4], iyh[4], izh[4];
    unsigned vm = 0;
    vm |= (unsigned)((w0 >> (ix0 & 63)) & 1ull) << 0;
    vm |= (unsigned)((w1 >> (ix1 & 63)) & 1ull) << 1;
    const int Ss[4]  = {S2, S3, S4, S5};
    const int CBo[4] = {CB2, CB3, CB4, CB5};
#pragma unroll
    for (int j = 0; j < 4; ++j) {
        const float inv = 1.0f / (float)(1 << j);      // 1, .5, .25, .125
        const float sx = qx*inv, sy = qy*inv, sz = qz*inv;
        const float bx = floorf(sx), by = floorf(sy), bz = floorf(sz);
        fxh[j] = sx-bx; fyh[j] = sy-by; fzh[j] = sz-bz;
        ixh[j] = (int)bx; iyh[j] = (int)by; izh[j] = (int)bz;
        const int C = Ss[j] - 1;
        const unsigned long long row = cbit25[CBo[j] + izh[j]*C + iyh[j]];
        vm |= (unsigned)((row >> ixh[j]) & 1ull) << (2 + j);
    }

#pragma unroll
    for (int f = 0; f < NF; ++f) acc[f] = 0.0f;

    // levels 0-1: gated gathers (gate == all 8 corner idx >= 0)
#pragma unroll
    for (int i = 0; i < 2; ++i) {
        if (vm & (1u << i)) {
            const float inv = (i == 0) ? 4.0f : 2.0f;  // exact pow2
            const float sx = qx*inv, sy = qy*inv, sz = qz*inv;
            const float bx = floorf(sx), by = floorf(sy), bz = floorf(sz);
            const unsigned h = (unsigned)(int)bx*P0 + (unsigned)(int)by*P1
                             + (unsigned)(int)bz*P2;
            const int* __restrict__ tab = fidx + (size_t)i * BTAB;
            int id[8];
#pragma unroll
            for (int k = 0; k < 8; ++k) {
                unsigned key = h;
                if (k & 4) key += P0;
                if (k & 2) key += P1;
                if (k & 1) key += P2;
                id[k] = tab[key & BMASK];
            }
            const float tx = sx - bx, ty = sy - by, tz = sz - bz;
            const float wxv[2] = {1.0f - tx, tx};
            const float wyv[2] = {1.0f - ty, ty};
            const float wzv[2] = {1.0f - tz, tz};
            const float* __restrict__ fb = feat + (size_t)i * (TTAB * NF);
#pragma unroll
            for (int k = 0; k < 8; ++k) {
                const float c = wxv[(k>>2)&1] * wyv[(k>>1)&1] * wzv[k&1];
                const float4* p = (const float4*)(fb + (size_t)id[k] * NF);
                const float4 lo = p[0], hi = p[1];
                acc[0]+=c*lo.x; acc[1]+=c*lo.y; acc[2]+=c*lo.z; acc[3]+=c*lo.w;
                acc[4]+=c*hi.x; acc[5]+=c*hi.y; acc[6]+=c*hi.z; acc[7]+=c*hi.w;
            }
        }
    }
    // levels 2-5
#pragma unroll
    for (int j = 0; j < 4; ++j) {
        if (vm & (1u << (2 + j))) {
            const int lvl = 2 + j;
            const unsigned h = (unsigned)ixh[j]*P0 + (unsigned)iyh[j]*P1
                             + (unsigned)izh[j]*P2;
            const int* __restrict__ tab = fidx + (size_t)lvl * BTAB;
            int id[8];
#pragma unroll
            for (int k = 0; k < 8; ++k) {
                unsigned key = h;
                if (k & 4) key += P0;
                if (k & 2) key += P1;
                if (k & 1) key += P2;
                id[k] = tab[key & BMASK];
            }
            const float wxv[2] = {1.0f - fxh[j], fxh[j]};
            const float wyv[2] = {1.0f - fyh[j], fyh[j]};
            const float wzv[2] = {1.0f - fzh[j], fzh[j]};
            const float* __restrict__ fb = feat + (size_t)lvl * (TTAB * NF);
#pragma unroll
            for (int k = 0; k < 8; ++k) {
                const float c = wxv[(k>>2)&1] * wyv[(k>>1)&1] * wzv[k&1];
                const float4* p = (const float4*)(fb + (size_t)id[k] * NF);
                const float4 lo = p[0], hi = p[1];
                acc[0]+=c*lo.x; acc[1]+=c*lo.y; acc[2]+=c*lo.z; acc[3]+=c*lo.w;
                acc[4]+=c*hi.x; acc[5]+=c*hi.y; acc[6]+=c*hi.z; acc[7]+=c*hi.w;
            }
        }
    }
}

// ---------------- plain per-point (ws-too-small fallback) -------------------
__device__ __forceinline__ void nhv_point(
    float qx, float qy, float qz,
    const float* __restrict__ feat, const int* __restrict__ fidx, float acc[NF])
{
    float fx[6], fy[6], fz[6];
    unsigned h[6];
#pragma unroll
    for (int i = 0; i < 6; ++i) {
        const float inv = 4.0f / (float)(1 << i);
        const float sx = qx*inv, sy = qy*inv, sz = qz*inv;
        const float bx = floorf(sx), by = floorf(sy), bz = floorf(sz);
        fx[i] = sx-bx; fy[i] = sy-by; fz[i] = sz-bz;
        h[i] = (unsigned)(int)bx*P0 + (unsigned)(int)by*P1 + (unsigned)(int)bz*P2;
    }
    int id[6][8];
#pragma unroll
    for (int i = 0; i < 6; ++i) {
        const int* __restrict__ tab = fidx + (size_t)i * BTAB;
#pragma unroll
        for (int k = 0; k < 8; ++k) {
            unsigned key = h[i];
            if (k & 4) key += P0;
            if (k & 2) key += P1;
            if (k & 1) key += P2;
            id[i][k] = tab[key & BMASK];
        }
    }
#pragma unroll
    for (int f = 0; f < NF; ++f) acc[f] = 0.0f;
#pragma unroll
    for (int i = 0; i < 6; ++i) {
        int mn = id[i][0];
#pragma unroll
        for (int k = 1; k < 8; ++k) mn = min(mn, id[i][k]);
        if (mn > -1) {
            const float wxv[2] = {1.0f - fx[i], fx[i]};
            const float wyv[2] = {1.0f - fy[i], fy[i]};
            const float wzv[2] = {1.0f - fz[i], fz[i]};
            const float* __restrict__ fb = feat + (size_t)i * (TTAB * NF);
#pragma unroll
            for (int k = 0; k < 8; ++k) {
                const float c = wxv[(k>>2)&1] * wyv[(k>>1)&1] * wzv[k&1];
                const float4* p = (const float4*)(fb + (size_t)id[i][k] * NF);
                const float4 lo = p[0], hi = p[1];
                acc[0]+=c*lo.x; acc[1]+=c*lo.y; acc[2]+=c*lo.z; acc[3]+=c*lo.w;
                acc[4]+=c*hi.x; acc[5]+=c*hi.y; acc[6]+=c*hi.z; acc[7]+=c*hi.w;
            }
        }
    }
}

// ---------------- binning ----------------
__device__ __forceinline__ unsigned expand4(unsigned v) {
    return (v & 1u) | ((v & 2u) << 2) | ((v & 4u) << 4) | ((v & 8u) << 6);
}
__device__ __forceinline__ unsigned bin_of(float x, float y, float z) {
    unsigned bx = min(15u, (unsigned)(int)(x * 0.32f));
    unsigned by = min(15u, (unsigned)(int)(y * 0.32f));
    unsigned bz = min(15u, (unsigned)(int)(z * 0.32f));
    return expand4(bx) | (expand4(by) << 1) | (expand4(bz) << 2);
}

// --- pre_k: occ2-5 grids || bm01 build (coalesced ballot) || histogram ------
__global__ __launch_bounds__(256) void pre_k(const int* __restrict__ fidx,
                                             unsigned long long* __restrict__ occ25,
                                             unsigned long long* __restrict__ bm01,
                                             const float* __restrict__ qp,
                                             unsigned* __restrict__ hist) {
    __shared__ unsigned lh[NBIN];
    const int t = threadIdx.x, b = blockIdx.x;
    if (b < OCCB) {
        int lvl, S, occoff, bb = b;
        if (bb < RB2)              { lvl = 2; S = S2; occoff = OCC2; }
        else if ((bb -= RB2) < RB3){ lvl = 3; S = S3; occoff = OCC3; }
        else if ((bb -= RB3) < RB4){ lvl = 4; S = S4; occoff = OCC4; }
        else        { bb -= RB4;     lvl = 5; S = S5; occoff = OCC5; }
        const int row  = bb * 4 + (t >> 6);
        const int lane = t & 63;
        if (row < S * S) {
            const int y = row % S, z = row / S;
            bool v = false;
            if (lane < S) {
                const unsigned key = ((unsigned)lane*P0 + (unsigned)y*P1
                                    + (unsigned)z*P2) & BMASK;
                v = fidx[(size_t)lvl * BTAB + key] >= 0;
            }
            const unsigned long long m = __ballot(v);
            if (lane == 0) occ25[occoff + row] = m;
        }
    } else if (b < OCCB + BM01B) {
        // bm01: wave w covers buckets [w*256,(w+1)*256); lane l: buckets 4l+k
        const int tid  = (b - OCCB) * 256 + t;
        const int w    = tid >> 6;
        const int lane = tid & 63;
        const i4 v = __builtin_nontemporal_load(
                        (const i4*)(fidx + (size_t)w * 256) + lane);
        const unsigned long long m0 = __ballot(v.x >= 0);
        const unsigned long long m1 = __ballot(v.y >= 0);
        const unsigned long long m2 = __ballot(v.z >= 0);
        const unsigned long long m3 = __ballot(v.w >= 0);
        if (lane == 0) {
            unsigned long long* d = bm01 + ((size_t)w << 2);
            d[0] = m0; d[1] = m1; d[2] = m2; d[3] = m3;
        }
    } else {
        const int bh = b - OCCB - BM01B;
        for (int i = t; i < NBIN; i += 256) lh[i] = 0u;
        __syncthreads();
        const int base = bh * PPB;
#pragma unroll
        for (int i = 0; i < ITER; ++i) {
            const int p = base + i * 256 + t;
            const float x = __builtin_nontemporal_load(qp + 3*p);
            const float y = __builtin_nontemporal_load(qp + 3*p + 1);
            const float z = __builtin_nontemporal_load(qp + 3*p + 2);
            atomicAdd(&lh[bin_of(x, y, z)], 1u);
        }
        __syncthreads();
        for (int i = t; i < NBIN; i += 256)
            __builtin_nontemporal_store(lh[i], hist + (size_t)bh * NBIN + i);
    }
}

// --- occ01_k: vertex-occupancy grids for levels 0-1 from bm01 (L2) ----------
__global__ __launch_bounds__(256) void occ01_k(
    const unsigned long long* __restrict__ bm01,
    unsigned long long* __restrict__ occ0,
    unsigned long long* __restrict__ occ1)
{
    const int wid  = (blockIdx.x * 256 + threadIdx.x) >> 6;
    const int lane = threadIdx.x & 63;
    if (wid >= OCC01_WAVES) return;

    int lvl, S, row, wblk;
    unsigned long long* dst;
    if (wid < OCC0W_CNT) {
        lvl = 0; S = L0S; row = wid >> 2; wblk = wid & 3; dst = occ0 + wid;
    } else {
        const int w1 = wid - OCC0W_CNT;
        lvl = 1; S = L1S; row = w1 >> 1; wblk = w1 & 1; dst = occ1 + w1;
    }
    const int z = row / S, y = row % S;
    const int x = wblk * 64 + lane;
    bool v = false;
    if (x < S) {
        const unsigned key = ((unsigned)x*P0 + (unsigned)y*P1 + (unsigned)z*P2) & BMASK;
        const unsigned B = (unsigned)lvl * BTAB + key;
        const unsigned long long word = bm01[((size_t)(B >> 8) << 2) | (B & 3u)];
        v = (word >> ((B >> 2) & 63u)) & 1ull;
    }
    const unsigned long long m = __ballot(v);
    if (lane == 0) *dst = m;
}

// ---- mid_k: colscan || cbit25 || cbit0 || cbit1 derivation -----------------
__global__ __launch_bounds__(256) void mid_k(unsigned* __restrict__ hist,
                                             unsigned* __restrict__ binbase,
                                             const unsigned long long* __restrict__ occ25,
                                             const unsigned long long* __restrict__ occ0,
                                             const unsigned long long* __restrict__ occ1,
                                             unsigned long long* __restrict__ cbit25,
                                             unsigned long long* __restrict__ cbit0,
                                             unsigned long long* __restrict__ cbit1) {
    const int t = threadIdx.x, b = blockIdx.x;
    if (b < 16) {
        const int bin = b * 256 + t;
        unsigned run = 0;
        for (int blk = 0; blk < SB; ++blk) {
            const unsigned v = hist[(size_t)blk * NBIN + bin];
            hist[(size_t)blk * NBIN + bin] = run;
            run += v;
        }
        binbase[bin] = run;
        return;
    }
    const int c = (b - 16) * 256 + t;
    if (c >= MIDC) return;
    if (c < CBW) {
        int S, occoff, cboff, local;
        if (c < CB3)      { S = S2; occoff = OCC2; cboff = CB2; local = c; }
        else if (c < CB4) { S = S3; occoff = OCC3; cboff = CB3; local = c - CB3; }
        else if (c < CB5) { S = S4; occoff = OCC4; cboff = CB4; local = c - CB4; }
        else              { S = S5; occoff = OCC5; cboff = CB5; local = c - CB5; }
        const int C = S - 1;
        const int cy = local % C, cz = local / C;
        const unsigned long long r00 = occ25[occoff +  cz      * S + cy    ];
        const unsigned long long r10 = occ25[occoff +  cz      * S + cy + 1];
        const unsigned long long r01 = occ25[occoff + (cz + 1) * S + cy    ];
        const unsigned long long r11 = occ25[occoff + (cz + 1) * S + cy + 1];
        cbit25[cboff + cz * C + cy] = (r00 & (r00 >> 1)) & (r10 & (r10 >> 1))
                                    & (r01 & (r01 >> 1)) & (r11 & (r11 >> 1));
    } else if (c < CBW + CB0_CNT) {
        const int c0 = c - CBW;
        const int w = c0 & 3, crow = c0 >> 2;
        const int cy = crow % L0C, cz = crow / L0C;
        unsigned long long res = ~0ull;
#pragma unroll
        for (int dy = 0; dy < 2; ++dy)
#pragma unroll
            for (int dz = 0; dz < 2; ++dz) {
                const unsigned long long* r =
                    occ0 + ((size_t)((cz + dz) * L0S + (cy + dy)) << 2);
                const unsigned long long a = r[w];
                const unsigned long long n = (w < 3) ? r[w + 1] : 0ull;
                res &= a & ((a >> 1) | (n << 63));
            }
        cbit0[c0] = res;
    } else {
        const int c1 = c - CBW - CB0_CNT;
        const int w = c1 & 1, crow = c1 >> 1;
        const int cy = crow % L1C, cz = crow / L1C;
        unsigned long long res = ~0ull;
#pragma unroll
        for (int dy = 0; dy < 2; ++dy)
#pragma unroll
            for (int dz = 0; dz < 2; ++dz) {
                const unsigned long long* r =
                    occ1 + ((size_t)((cz + dz) * L1S + (cy + dy)) << 1);
                const unsigned long long a = r[w];
                const unsigned long long n = (w < 1) ? r[w + 1] : 0ull;
                res &= a & ((a >> 1) | (n << 63));
            }
        cbit1[c1] = res;
    }
}

__global__ __launch_bounds__(256) void binscan_k(unsigned* __restrict__ binbase) {
    __shared__ unsigned tot[256];
    const int t = threadIdx.x;
    unsigned v[16];
    unsigned s = 0;
#pragma unroll
    for (int i = 0; i < 16; ++i) { v[i] = s; s += binbase[t * 16 + i]; }
    tot[t] = s;
    __syncthreads();
    for (int d = 1; d < 256; d <<= 1) {
        const unsigned x = (t >= d) ? tot[t - d] : 0u;
        __syncthreads();
        tot[t] += x;
        __syncthreads();
    }
    const unsigned cb = tot[t] - s;
#pragma unroll
    for (int i = 0; i < 16; ++i) binbase[t * 16 + i] = cb + v[i];
}

__global__ __launch_bounds__(256) void scatter_k(const float* __restrict__ qp,
                                                 const unsigned* __restrict__ hist,
                                                 const unsigned* __restrict__ binbase,
                                                 float4* __restrict__ sorted) {
    __shared__ unsigned cur[NBIN];
    const int b = blockIdx.x, t = threadIdx.x;
    for (int i = t; i < NBIN; i += 256)
        cur[i] = binbase[i] + hist[(size_t)b * NBIN + i];
    __syncthreads();
    const int base = b * PPB;
#pragma unroll
    for (int i = 0; i < ITER; ++i) {
        const int p = base + i * 256 + t;
        const float x = __builtin_nontemporal_load(qp + 3*p);
        const float y = __builtin_nontemporal_load(qp + 3*p + 1);
        const float z = __builtin_nontemporal_load(qp + 3*p + 2);
        const unsigned slot = atomicAdd(&cur[bin_of(x, y, z)], 1u);
        const f4 v = {x, y, z, __uint_as_float((unsigned)p)};
        __builtin_nontemporal_store(v, (f4*)sorted + slot);
    }
}

// ------- stage 2: per-bin 64-bucket counting sort (6-bit sub-Morton) --------
__global__ __launch_bounds__(256) void binsort_k(float4* __restrict__ sorted,
                                                 const unsigned* __restrict__ binbase) {
    __shared__ float4        pts[BCAP];
    __shared__ unsigned char sk[BCAP];
    __shared__ unsigned      cnt[64];
    const int bin = blockIdx.x, t = threadIdx.x;
    const unsigned start = binbase[bin];
    const unsigned end   = (bin < NBIN - 1) ? binbase[bin + 1] : (unsigned)NPTS;
    const int n = (int)(end - start);
    if (n <= 1 || n > BCAP) return;

    if (t < 64) cnt[t] = 0u;
    __syncthreads();
#pragma unroll
    for (int r = 0; r < BCAP / 256; ++r) {
        const int i = r * 256 + t;
        if (i < n) {
            const f4 pv = __builtin_nontemporal_load((const f4*)sorted + (start + i));
            const float4 p = make_float4(pv.x, pv.y, pv.z, pv.w);
            pts[i] = p;
            const unsigned ux = (unsigned)(int)(p.x * 1.28f) & 3u;
            const unsigned uy = (unsigned)(int)(p.y * 1.28f) & 3u;
            const unsigned uz = (unsigned)(int)(p.z * 1.28f) & 3u;
            const unsigned s = (ux & 1u) | ((uy & 1u) << 1) | ((uz & 1u) << 2)
                             | ((ux >> 1) << 3) | ((uy >> 1) << 4) | ((uz >> 1) << 5);
            sk[i] = (unsigned char)s;
            atomicAdd(&cnt[s], 1u);
        }
    }
    __syncthreads();
    if (t == 0) {
        unsigned run = 0;
#pragma unroll
        for (int i = 0; i < 64; ++i) { const unsigned v = cnt[i]; cnt[i] = run; run += v; }
    }
    __syncthreads();
#pragma unroll
    for (int r = 0; r < BCAP / 256; ++r) {
        const int i = r * 256 + t;
        if (i < n) {
            const unsigned dest = atomicAdd(&cnt[sk[i]], 1u);
            const float4 p = pts[i];
            const f4 v = {p.x, p.y, p.z, p.w};
            __builtin_nontemporal_store(v, (f4*)sorted + (start + dest));
        }
    }
}

// ---------------- main kernel (flat, XCD-slab swizzle) ----------------------
__global__ __launch_bounds__(256) void nhv_main_k(
    const float4* __restrict__ sp, const float* __restrict__ feat,
    const int* __restrict__ fidx,
    const unsigned long long* __restrict__ cbit25,
    const unsigned long long* __restrict__ cbit0,
    const unsigned long long* __restrict__ cbit1,
    float* __restrict__ out)
{
    const int nwg = NPTS / 256;
    const int bid = blockIdx.x;
    const int swz = (bid & 7) * (nwg >> 3) + (bid >> 3);
    const int j   = swz * 256 + (int)threadIdx.x;

    const f4 s = __builtin_nontemporal_load((const f4*)sp + j);
    float acc[NF];
    nhv_point_g(s.x, s.y, s.z, feat, fidx, cbit25, cbit0, cbit1, acc);
    const unsigned n = __float_as_uint(s.w);
    f4* o = (f4*)(out + (size_t)n * NF);
    f4 lo = {acc[0], acc[1], acc[2], acc[3]};
    f4 hi = {acc[4], acc[5], acc[6], acc[7]};
    __builtin_nontemporal_store(lo, o);
    __builtin_nontemporal_store(hi, o + 1);
}

// ---------------- fallback ----------------
__global__ __launch_bounds__(256) void nhv_direct_k(
    const float* __restrict__ qp, const float* __restrict__ feat,
    const int* __restrict__ fidx, float* __restrict__ out)
{
    const int n = blockIdx.x * 256 + threadIdx.x;
    if (n >= NPTS) return;
    float acc[NF];
    nhv_point(qp[3*n], qp[3*n+1], qp[3*n+2], feat, fidx, acc);
    float4* o = (float4*)(out + (size_t)n * NF);
    o[0] = make_float4(acc[0], acc[1], acc[2], acc[3]);
    o[1] = make_float4(acc[4], acc[5], acc[6], acc[7]);
}

extern "C" void kernel_launch(void* const* d_in, const int* in_sizes, int n_in,
                              void* d_out, int out_size, void* d_ws, size_t ws_size,
                              hipStream_t stream) {
    const float* qp   = (const float*)d_in[0];
    const float* feat = (const float*)d_in[1];
    const int*   fidx = (const int*)d_in[2];
    float*       out  = (float*)d_out;

    if (ws_size >= WS_FULL) {
        // ws (read by main): sorted | cbit25 | cbit0 | cbit1 | binbase
        float4*             sorted  = (float4*)d_ws;
        unsigned long long* cbit25  = (unsigned long long*)((char*)d_ws + CB25_OFF);
        unsigned long long* cbit0   = (unsigned long long*)((char*)d_ws + CB0_OFF);
        unsigned long long* cbit1   = (unsigned long long*)((char*)d_ws + CB1_OFF);
        unsigned*           binbase = (unsigned*)((char*)d_ws + BB_OFF);
        // d_out scratch (all consumed before main overwrites out):
        unsigned*           hist  = (unsigned*)d_out;
        unsigned long long* bm01  = (unsigned long long*)((char*)d_out + OUT_BM01_OFF);
        unsigned long long* occ25 = (unsigned long long*)((char*)d_out + OUT_OCC25_OFF);
        unsigned long long* occ0  = (unsigned long long*)((char*)d_out + OUT_OCC0_OFF);
        unsigned long long* occ1  = (unsigned long long*)((char*)d_out + OUT_OCC1_OFF);

        pre_k<<<dim3(OCCB + BM01B + SB), dim3(256), 0, stream>>>(fidx, occ25, bm01, qp, hist);
        occ01_k<<<dim3(OCC01_B), dim3(256), 0, stream>>>(bm01, occ0, occ1);
        mid_k<<<dim3(MIDB), dim3(256), 0, stream>>>(hist, binbase, occ25, occ0, occ1,
                                                    cbit25, cbit0, cbit1);
        binscan_k<<<dim3(1), dim3(256), 0, stream>>>(binbase);
        scatter_k<<<dim3(SB), dim3(256), 0, stream>>>(qp, hist, binbase, sorted);
        binsort_k<<<dim3(NBIN), dim3(256), 0, stream>>>(sorted, binbase);
        nhv_main_k<<<dim3(NPTS/256), dim3(256), 0, stream>>>(sorted, feat, fidx,
                                                             cbit25, cbit0, cbit1, out);
    } else {
        nhv_direct_k<<<dim3(NPTS/256), dim3(256), 0, stream>>>(qp, feat, fidx, out);
    }
}